// Round 1
// baseline (2676.071 us; speedup 1.0000x reference)
//
#include <hip/hip_runtime.h>

#define B_ 8
#define S_ 2048
#define DIM_ 2048
#define HD_ 128

// ---------------------------------------------------------------------------
// Projection GEMM: qkv[s][b][j*128+n] = x[(b,s),:] @ W_j + bias_j
// BM=128, BN=128(=HD), BK=32, 256 threads, 8x8 micro-tile per thread.
// Grid: (M/128 = 128, 3)  -- blockIdx.y selects q/k/v.
// ---------------------------------------------------------------------------
__global__ __launch_bounds__(256) void proj_kernel(
    const float* __restrict__ x,
    const float* __restrict__ Wq, const float* __restrict__ bq,
    const float* __restrict__ Wk, const float* __restrict__ bk,
    const float* __restrict__ Wv, const float* __restrict__ bv,
    float* __restrict__ qkv)
{
    __shared__ __align__(16) float As[32][132];  // [k][m], padded
    __shared__ __align__(16) float Bs[32][132];  // [k][n], padded

    const int jsel = blockIdx.y;
    const float* Wj   = (jsel == 0) ? Wq : (jsel == 1) ? Wk : Wv;
    const float* bias = (jsel == 0) ? bq : (jsel == 1) ? bk : bv;

    const int m0 = blockIdx.x * 128;
    const int t  = threadIdx.x;
    const int tx = t & 15;        // n dimension (8 cols each)
    const int ty = t >> 4;        // m dimension (8 rows each)

    float acc[8][8];
    #pragma unroll
    for (int i = 0; i < 8; ++i)
        #pragma unroll
        for (int j = 0; j < 8; ++j) acc[i][j] = 0.f;

    for (int k0 = 0; k0 < DIM_; k0 += 32) {
        // --- stage x tile (128 rows x 32 k), store transposed [k][m]
        #pragma unroll
        for (int p = 0; p < 4; ++p) {
            int slot = t + p * 256;            // 0..1023
            int row  = slot >> 3;              // 0..127
            int c4   = slot & 7;               // 0..7 (float4 along k)
            float4 v = *(const float4*)&x[(size_t)(m0 + row) * DIM_ + k0 + c4 * 4];
            As[c4 * 4 + 0][row] = v.x;
            As[c4 * 4 + 1][row] = v.y;
            As[c4 * 4 + 2][row] = v.z;
            As[c4 * 4 + 3][row] = v.w;
        }
        // --- stage W tile (32 k x 128 n), natural layout
        #pragma unroll
        for (int p = 0; p < 4; ++p) {
            int slot = t + p * 256;            // 0..1023
            int kr   = slot >> 5;              // 0..31
            int n4   = slot & 31;              // 0..31
            *(float4*)&Bs[kr][n4 * 4] =
                *(const float4*)&Wj[(size_t)(k0 + kr) * HD_ + n4 * 4];
        }
        __syncthreads();

        #pragma unroll 4
        for (int kk = 0; kk < 32; ++kk) {
            float a[8], b[8];
            *(float4*)&a[0] = *(const float4*)&As[kk][ty * 8];
            *(float4*)&a[4] = *(const float4*)&As[kk][ty * 8 + 4];
            *(float4*)&b[0] = *(const float4*)&Bs[kk][tx * 8];
            *(float4*)&b[4] = *(const float4*)&Bs[kk][tx * 8 + 4];
            #pragma unroll
            for (int i = 0; i < 8; ++i)
                #pragma unroll
                for (int j = 0; j < 8; ++j)
                    acc[i][j] = fmaf(a[i], b[j], acc[i][j]);
        }
        __syncthreads();
    }

    // epilogue: add bias, write time-major qkv[s][b][jsel*128 + n]
    #pragma unroll
    for (int i = 0; i < 8; ++i) {
        int m = m0 + ty * 8 + i;
        int bb = m >> 11;          // batch
        int ss = m & 2047;         // seq pos
        size_t base = ((size_t)ss * B_ + bb) * 384 + jsel * 128 + tx * 8;
        #pragma unroll
        for (int j = 0; j < 8; ++j)
            qkv[base + j] = acc[i][j] + bias[tx * 8 + j];
    }
}

// ---------------------------------------------------------------------------
// Sequential scan: one block per batch, 1024 threads.
// W[128][128] lives in registers: thread t owns row r = t>>3, cols (t&7)*16 .. +15.
// Per step: y = W q ; err = W k - v ; W -= lr * err * k^T ; emit y.
// Double-buffered LDS staging of qkv[s] with register prefetch of s+1.
// ---------------------------------------------------------------------------
__global__ __launch_bounds__(1024) void scan_kernel(
    const float* __restrict__ qkv,   // [S][B][384]
    const float* __restrict__ state, // [B][128][128]
    const float* __restrict__ lrp,
    float* __restrict__ ys,          // [S][B][128]
    float* __restrict__ Wf)          // [B][128][128] (d_out tail)
{
    const int b = blockIdx.x;
    const int t = threadIdx.x;
    const int r = t >> 3;   // row 0..127
    const int h = t & 7;    // col-chunk 0..7 (16 cols each)
    const float lr = lrp[0];

    float w[16];
    {
        size_t sb = ((size_t)b * HD_ + r) * HD_ + h * 16;
        #pragma unroll
        for (int p = 0; p < 4; ++p)
            *(float4*)&w[p * 4] = *(const float4*)&state[sb + p * 4];
    }

    __shared__ __align__(16) float buf[2][384];

    // preload step 0
    if (t < 96) {
        float4 v = ((const float4*)(qkv + (size_t)b * 384))[t];
        *(float4*)&buf[0][t * 4] = v;
    }
    __syncthreads();

    for (int s = 0; s < S_; ++s) {
        const float* cur = buf[s & 1];

        // prefetch next step's qkv into registers (store to LDS later)
        float4 pf;
        const bool do_pf = (s + 1 < S_) && (t < 96);
        if (do_pf)
            pf = ((const float4*)(qkv + ((size_t)(s + 1) * B_ + b) * 384))[t];

        float q[16], k[16];
        #pragma unroll
        for (int p = 0; p < 4; ++p) {
            *(float4*)&q[p * 4] = *(const float4*)&cur[h * 16 + p * 4];
            *(float4*)&k[p * 4] = *(const float4*)&cur[128 + h * 16 + p * 4];
        }
        float vr = cur[256 + r];

        // partial dots with 4 accumulators each
        float y0 = 0.f, y1 = 0.f, y2 = 0.f, y3 = 0.f;
        float e0 = 0.f, e1 = 0.f, e2 = 0.f, e3 = 0.f;
        #pragma unroll
        for (int p = 0; p < 16; p += 4) {
            y0 = fmaf(w[p + 0], q[p + 0], y0);
            y1 = fmaf(w[p + 1], q[p + 1], y1);
            y2 = fmaf(w[p + 2], q[p + 2], y2);
            y3 = fmaf(w[p + 3], q[p + 3], y3);
            e0 = fmaf(w[p + 0], k[p + 0], e0);
            e1 = fmaf(w[p + 1], k[p + 1], e1);
            e2 = fmaf(w[p + 2], k[p + 2], e2);
            e3 = fmaf(w[p + 3], k[p + 3], e3);
        }
        float yp = (y0 + y1) + (y2 + y3);
        float ep = (e0 + e1) + (e2 + e3);

        // reduce across the 8 col-chunk lanes (low 3 bits of lane id)
        #pragma unroll
        for (int m = 1; m <= 4; m <<= 1) {
            yp += __shfl_xor(yp, m);
            ep += __shfl_xor(ep, m);
        }

        float err = ep - vr;
        float c = -lr * err;
        #pragma unroll
        for (int j = 0; j < 16; ++j)
            w[j] = fmaf(c, k[j], w[j]);

        if (h == 0)
            ys[((size_t)s * B_ + b) * HD_ + r] = yp;

        if (do_pf)
            *(float4*)&buf[(s + 1) & 1][t * 4] = pf;

        __syncthreads();
    }

    // write final state
    {
        size_t sb = ((size_t)b * HD_ + r) * HD_ + h * 16;
        #pragma unroll
        for (int p = 0; p < 4; ++p)
            *(float4*)&Wf[sb + p * 4] = *(const float4*)&w[p * 4];
    }
}

// ---------------------------------------------------------------------------
// Output projection: out[(b,s), n] = ys[s][b][:] @ Wo + bo
// BM=128, BN=128, BK=64, 256 threads, 8x8 micro. Grid: (128, 16).
// ---------------------------------------------------------------------------
__global__ __launch_bounds__(256) void outproj_kernel(
    const float* __restrict__ ys,   // [S][B][128]
    const float* __restrict__ Wo,   // [128][2048]
    const float* __restrict__ bo,   // [2048]
    float* __restrict__ out)        // [B*S][2048]
{
    __shared__ __align__(16) float As[64][132];  // [k][m]
    __shared__ __align__(16) float Bs[64][132];  // [k][n]

    const int m0 = blockIdx.x * 128;
    const int n0 = blockIdx.y * 128;
    const int bb = m0 >> 11;
    const int s0 = m0 & 2047;
    const int t  = threadIdx.x;
    const int tx = t & 15;
    const int ty = t >> 4;

    float acc[8][8];
    #pragma unroll
    for (int i = 0; i < 8; ++i)
        #pragma unroll
        for (int j = 0; j < 8; ++j) acc[i][j] = 0.f;

    for (int k0 = 0; k0 < HD_; k0 += 64) {
        // ys tile: 128 rows x 64 k  -> transposed
        #pragma unroll
        for (int p = 0; p < 8; ++p) {
            int slot = t + p * 256;        // 0..2047
            int row  = slot >> 4;          // 0..127
            int c4   = slot & 15;          // 0..15
            float4 v = *(const float4*)&ys[((size_t)(s0 + row) * B_ + bb) * HD_ + k0 + c4 * 4];
            As[c4 * 4 + 0][row] = v.x;
            As[c4 * 4 + 1][row] = v.y;
            As[c4 * 4 + 2][row] = v.z;
            As[c4 * 4 + 3][row] = v.w;
        }
        // Wo tile: 64 k x 128 n
        #pragma unroll
        for (int p = 0; p < 8; ++p) {
            int slot = t + p * 256;        // 0..2047
            int kr   = slot >> 5;          // 0..63
            int n4   = slot & 31;          // 0..31
            *(float4*)&Bs[kr][n4 * 4] =
                *(const float4*)&Wo[(size_t)(k0 + kr) * DIM_ + n0 + n4 * 4];
        }
        __syncthreads();

        #pragma unroll 4
        for (int kk = 0; kk < 64; ++kk) {
            float a[8], bfr[8];
            *(float4*)&a[0]   = *(const float4*)&As[kk][ty * 8];
            *(float4*)&a[4]   = *(const float4*)&As[kk][ty * 8 + 4];
            *(float4*)&bfr[0] = *(const float4*)&Bs[kk][tx * 8];
            *(float4*)&bfr[4] = *(const float4*)&Bs[kk][tx * 8 + 4];
            #pragma unroll
            for (int i = 0; i < 8; ++i)
                #pragma unroll
                for (int j = 0; j < 8; ++j)
                    acc[i][j] = fmaf(a[i], bfr[j], acc[i][j]);
        }
        __syncthreads();
    }

    #pragma unroll
    for (int i = 0; i < 8; ++i) {
        size_t m = m0 + ty * 8 + i;
        #pragma unroll
        for (int j = 0; j < 8; ++j)
            out[m * DIM_ + n0 + tx * 8 + j] = acc[i][j] + bo[n0 + tx * 8 + j];
    }
}

// ---------------------------------------------------------------------------
extern "C" void kernel_launch(void* const* d_in, const int* in_sizes, int n_in,
                              void* d_out, int out_size, void* d_ws, size_t ws_size,
                              hipStream_t stream)
{
    const float* x  = (const float*)d_in[0];
    const float* st = (const float*)d_in[1];
    const float* Wq = (const float*)d_in[2];
    const float* bq = (const float*)d_in[3];
    const float* Wk = (const float*)d_in[4];
    const float* bk = (const float*)d_in[5];
    const float* Wv = (const float*)d_in[6];
    const float* bv = (const float*)d_in[7];
    const float* Wo = (const float*)d_in[8];
    const float* bo = (const float*)d_in[9];
    const float* lr = (const float*)d_in[10];

    float* out = (float*)d_out;
    float* Wf  = out + (size_t)B_ * S_ * DIM_;   // final state, concatenated after out

    float* qkv = (float*)d_ws;                       // [S][B][384]  (25.2 MB)
    float* ys  = qkv + (size_t)S_ * B_ * 384;        // [S][B][128]  (8.4 MB)

    dim3 gp(128, 3);
    proj_kernel<<<gp, 256, 0, stream>>>(x, Wq, bq, Wk, bk, Wv, bv, qkv);

    scan_kernel<<<8, 1024, 0, stream>>>(qkv, st, lr, ys, Wf);

    dim3 go(128, 16);
    outproj_kernel<<<go, 256, 0, stream>>>(ys, Wo, bo, out);
}

// Round 2
// 1339.543 us; speedup vs baseline: 1.9977x; 1.9977x over previous
//
#include <hip/hip_runtime.h>

#define B_ 8
#define S_ 2048
#define DIM_ 2048
#define HD_ 128

// ---------------------------------------------------------------------------
// Projection GEMM: qkv[s][b][j*128+n] = x[(b,s),:] @ W_j + bias_j
// BM=128, BN=128(=HD), BK=32, 256 threads, 8x8 micro-tile per thread.
// Grid: (M/128 = 128, 3)  -- blockIdx.y selects q/k/v.
// ---------------------------------------------------------------------------
__global__ __launch_bounds__(256) void proj_kernel(
    const float* __restrict__ x,
    const float* __restrict__ Wq, const float* __restrict__ bq,
    const float* __restrict__ Wk, const float* __restrict__ bk,
    const float* __restrict__ Wv, const float* __restrict__ bv,
    float* __restrict__ qkv)
{
    __shared__ __align__(16) float As[32][132];  // [k][m], padded
    __shared__ __align__(16) float Bs[32][132];  // [k][n], padded

    const int jsel = blockIdx.y;
    const float* Wj   = (jsel == 0) ? Wq : (jsel == 1) ? Wk : Wv;
    const float* bias = (jsel == 0) ? bq : (jsel == 1) ? bk : bv;

    const int m0 = blockIdx.x * 128;
    const int t  = threadIdx.x;
    const int tx = t & 15;        // n dimension (8 cols each)
    const int ty = t >> 4;        // m dimension (8 rows each)

    float acc[8][8];
    #pragma unroll
    for (int i = 0; i < 8; ++i)
        #pragma unroll
        for (int j = 0; j < 8; ++j) acc[i][j] = 0.f;

    for (int k0 = 0; k0 < DIM_; k0 += 32) {
        #pragma unroll
        for (int p = 0; p < 4; ++p) {
            int slot = t + p * 256;            // 0..1023
            int row  = slot >> 3;              // 0..127
            int c4   = slot & 7;               // 0..7 (float4 along k)
            float4 v = *(const float4*)&x[(size_t)(m0 + row) * DIM_ + k0 + c4 * 4];
            As[c4 * 4 + 0][row] = v.x;
            As[c4 * 4 + 1][row] = v.y;
            As[c4 * 4 + 2][row] = v.z;
            As[c4 * 4 + 3][row] = v.w;
        }
        #pragma unroll
        for (int p = 0; p < 4; ++p) {
            int slot = t + p * 256;            // 0..1023
            int kr   = slot >> 5;              // 0..31
            int n4   = slot & 31;              // 0..31
            *(float4*)&Bs[kr][n4 * 4] =
                *(const float4*)&Wj[(size_t)(k0 + kr) * HD_ + n4 * 4];
        }
        __syncthreads();

        #pragma unroll 4
        for (int kk = 0; kk < 32; ++kk) {
            float a[8], b[8];
            *(float4*)&a[0] = *(const float4*)&As[kk][ty * 8];
            *(float4*)&a[4] = *(const float4*)&As[kk][ty * 8 + 4];
            *(float4*)&b[0] = *(const float4*)&Bs[kk][tx * 8];
            *(float4*)&b[4] = *(const float4*)&Bs[kk][tx * 8 + 4];
            #pragma unroll
            for (int i = 0; i < 8; ++i)
                #pragma unroll
                for (int j = 0; j < 8; ++j)
                    acc[i][j] = fmaf(a[i], b[j], acc[i][j]);
        }
        __syncthreads();
    }

    #pragma unroll
    for (int i = 0; i < 8; ++i) {
        int m = m0 + ty * 8 + i;
        int bb = m >> 11;          // batch
        int ss = m & 2047;         // seq pos
        size_t base = ((size_t)ss * B_ + bb) * 384 + jsel * 128 + tx * 8;
        #pragma unroll
        for (int j = 0; j < 8; ++j)
            qkv[base + j] = acc[i][j] + bias[tx * 8 + j];
    }
}

// ---------------------------------------------------------------------------
// Row-parallel sequential scan.
// W's rows evolve independently: W_i <- W_i - lr*(W_i.k - v_i)*k, y_i = W_i.q.
// One WAVE (64 threads) owns 8 rows of one batch: row = t>>3, col-chunk
// (t&7)*16. No __syncthreads anywhere; reductions are 3 shfl_xor over the
// 8 lanes of a row. q/k/v software-pipelined 3-4 steps ahead in 4 register
// buffer sets. blockIdx&7 = batch so a batch's 16 waves share one XCD's L2.
// ---------------------------------------------------------------------------
__global__ __launch_bounds__(64) void scan_kernel(
    const float* __restrict__ qkv,   // [S][B][384]
    const float* __restrict__ state, // [B][128][128]
    const float* __restrict__ lrp,
    float* __restrict__ ys,          // [S][B][128]
    float* __restrict__ Wf)          // [B][128][128]
{
    const int b    = blockIdx.x & 7;
    const int g    = blockIdx.x >> 3;   // row group 0..15
    const int t    = threadIdx.x;
    const int row  = t >> 3;            // 0..7
    const int ch   = t & 7;             // col chunk (16 cols)
    const int grow = g * 8 + row;       // global row 0..127
    const float lr = lrp[0];

    float w[16];
    {
        const float* ws = state + ((size_t)b * HD_ + grow) * HD_ + ch * 16;
        #pragma unroll
        for (int p = 0; p < 4; ++p)
            *(float4*)&w[p * 4] = *(const float4*)&ws[p * 4];
    }

    float Q[4][16], K[4][16], V[4];

#define LOADSTEP(buf, sidx) do {                                          \
        const float* pp = qkv + ((size_t)(sidx) * B_ + b) * 384;          \
        _Pragma("unroll")                                                 \
        for (int p = 0; p < 4; ++p) {                                     \
            *(float4*)&Q[buf][p * 4] = *(const float4*)&pp[ch * 16 + p * 4];        \
            *(float4*)&K[buf][p * 4] = *(const float4*)&pp[128 + ch * 16 + p * 4];  \
        }                                                                 \
        V[buf] = pp[256 + grow];                                          \
    } while (0)

#define STEP(buf, s) do {                                                 \
        float e0 = 0.f, e1 = 0.f, e2 = 0.f, e3 = 0.f;                     \
        float y0 = 0.f, y1 = 0.f, y2 = 0.f, y3 = 0.f;                     \
        _Pragma("unroll")                                                 \
        for (int p = 0; p < 16; p += 4) {                                 \
            e0 = fmaf(w[p + 0], K[buf][p + 0], e0);                       \
            e1 = fmaf(w[p + 1], K[buf][p + 1], e1);                       \
            e2 = fmaf(w[p + 2], K[buf][p + 2], e2);                       \
            e3 = fmaf(w[p + 3], K[buf][p + 3], e3);                       \
            y0 = fmaf(w[p + 0], Q[buf][p + 0], y0);                       \
            y1 = fmaf(w[p + 1], Q[buf][p + 1], y1);                       \
            y2 = fmaf(w[p + 2], Q[buf][p + 2], y2);                       \
            y3 = fmaf(w[p + 3], Q[buf][p + 3], y3);                       \
        }                                                                 \
        float ep = (e0 + e1) + (e2 + e3);                                 \
        float yp = (y0 + y1) + (y2 + y3);                                 \
        ep += __shfl_xor(ep, 1);                                          \
        yp += __shfl_xor(yp, 1);                                          \
        ep += __shfl_xor(ep, 2);                                          \
        yp += __shfl_xor(yp, 2);                                          \
        ep += __shfl_xor(ep, 4);                                          \
        yp += __shfl_xor(yp, 4);                                          \
        float c = -lr * (ep - V[buf]);                                    \
        _Pragma("unroll")                                                 \
        for (int j = 0; j < 16; ++j)                                      \
            w[j] = fmaf(c, K[buf][j], w[j]);                              \
        if (ch == 0)                                                      \
            ys[((size_t)(s) * B_ + b) * HD_ + grow] = yp;                 \
    } while (0)

    LOADSTEP(0, 0);
    LOADSTEP(1, 1);
    LOADSTEP(2, 2);
    LOADSTEP(3, 3);

    for (int s = 0; s < S_; s += 4) {
        STEP(0, s);
        { int sn = s + 4 < S_ ? s + 4 : S_ - 1; LOADSTEP(0, sn); }
        STEP(1, s + 1);
        { int sn = s + 5 < S_ ? s + 5 : S_ - 1; LOADSTEP(1, sn); }
        STEP(2, s + 2);
        { int sn = s + 6 < S_ ? s + 6 : S_ - 1; LOADSTEP(2, sn); }
        STEP(3, s + 3);
        { int sn = s + 7 < S_ ? s + 7 : S_ - 1; LOADSTEP(3, sn); }
    }

#undef LOADSTEP
#undef STEP

    {
        float* wd = Wf + ((size_t)b * HD_ + grow) * HD_ + ch * 16;
        #pragma unroll
        for (int p = 0; p < 4; ++p)
            *(float4*)&wd[p * 4] = *(const float4*)&w[p * 4];
    }
}

// ---------------------------------------------------------------------------
// Output projection: out[(b,s), n] = ys[s][b][:] @ Wo + bo
// BM=128, BN=128, BK=64, 256 threads, 8x8 micro. Grid: (128, 16).
// ---------------------------------------------------------------------------
__global__ __launch_bounds__(256) void outproj_kernel(
    const float* __restrict__ ys,   // [S][B][128]
    const float* __restrict__ Wo,   // [128][2048]
    const float* __restrict__ bo,   // [2048]
    float* __restrict__ out)        // [B*S][2048]
{
    __shared__ __align__(16) float As[64][132];  // [k][m]
    __shared__ __align__(16) float Bs[64][132];  // [k][n]

    const int m0 = blockIdx.x * 128;
    const int n0 = blockIdx.y * 128;
    const int bb = m0 >> 11;
    const int s0 = m0 & 2047;
    const int t  = threadIdx.x;
    const int tx = t & 15;
    const int ty = t >> 4;

    float acc[8][8];
    #pragma unroll
    for (int i = 0; i < 8; ++i)
        #pragma unroll
        for (int j = 0; j < 8; ++j) acc[i][j] = 0.f;

    for (int k0 = 0; k0 < HD_; k0 += 64) {
        #pragma unroll
        for (int p = 0; p < 8; ++p) {
            int slot = t + p * 256;        // 0..2047
            int row  = slot >> 4;          // 0..127
            int c4   = slot & 15;          // 0..15
            float4 v = *(const float4*)&ys[((size_t)(s0 + row) * B_ + bb) * HD_ + k0 + c4 * 4];
            As[c4 * 4 + 0][row] = v.x;
            As[c4 * 4 + 1][row] = v.y;
            As[c4 * 4 + 2][row] = v.z;
            As[c4 * 4 + 3][row] = v.w;
        }
        #pragma unroll
        for (int p = 0; p < 8; ++p) {
            int slot = t + p * 256;        // 0..2047
            int kr   = slot >> 5;          // 0..63
            int n4   = slot & 31;          // 0..31
            *(float4*)&Bs[kr][n4 * 4] =
                *(const float4*)&Wo[(size_t)(k0 + kr) * DIM_ + n0 + n4 * 4];
        }
        __syncthreads();

        #pragma unroll 4
        for (int kk = 0; kk < 64; ++kk) {
            float a[8], bfr[8];
            *(float4*)&a[0]   = *(const float4*)&As[kk][ty * 8];
            *(float4*)&a[4]   = *(const float4*)&As[kk][ty * 8 + 4];
            *(float4*)&bfr[0] = *(const float4*)&Bs[kk][tx * 8];
            *(float4*)&bfr[4] = *(const float4*)&Bs[kk][tx * 8 + 4];
            #pragma unroll
            for (int i = 0; i < 8; ++i)
                #pragma unroll
                for (int j = 0; j < 8; ++j)
                    acc[i][j] = fmaf(a[i], bfr[j], acc[i][j]);
        }
        __syncthreads();
    }

    #pragma unroll
    for (int i = 0; i < 8; ++i) {
        size_t m = m0 + ty * 8 + i;
        #pragma unroll
        for (int j = 0; j < 8; ++j)
            out[m * DIM_ + n0 + tx * 8 + j] = acc[i][j] + bo[n0 + tx * 8 + j];
    }
}

// ---------------------------------------------------------------------------
extern "C" void kernel_launch(void* const* d_in, const int* in_sizes, int n_in,
                              void* d_out, int out_size, void* d_ws, size_t ws_size,
                              hipStream_t stream)
{
    const float* x  = (const float*)d_in[0];
    const float* st = (const float*)d_in[1];
    const float* Wq = (const float*)d_in[2];
    const float* bq = (const float*)d_in[3];
    const float* Wk = (const float*)d_in[4];
    const float* bk = (const float*)d_in[5];
    const float* Wv = (const float*)d_in[6];
    const float* bv = (const float*)d_in[7];
    const float* Wo = (const float*)d_in[8];
    const float* bo = (const float*)d_in[9];
    const float* lr = (const float*)d_in[10];

    float* out = (float*)d_out;
    float* Wf  = out + (size_t)B_ * S_ * DIM_;   // final state, after out

    float* qkv = (float*)d_ws;                   // [S][B][384]
    float* ys  = qkv + (size_t)S_ * B_ * 384;    // [S][B][128]

    dim3 gp(128, 3);
    proj_kernel<<<gp, 256, 0, stream>>>(x, Wq, bq, Wk, bk, Wv, bv, qkv);

    scan_kernel<<<128, 64, 0, stream>>>(qkv, st, lr, ys, Wf);

    dim3 go(128, 16);
    outproj_kernel<<<go, 256, 0, stream>>>(ys, Wo, bo, out);
}

// Round 3
// 1333.795 us; speedup vs baseline: 2.0064x; 1.0043x over previous
//
#include <hip/hip_runtime.h>

#define B_ 8
#define S_ 2048
#define DIM_ 2048
#define HD_ 128

// ---------------------------------------------------------------------------
// Projection GEMM: qkv[s][b][j*128+n] = x[(b,s),:] @ W_j + bias_j
// ---------------------------------------------------------------------------
__global__ __launch_bounds__(256) void proj_kernel(
    const float* __restrict__ x,
    const float* __restrict__ Wq, const float* __restrict__ bq,
    const float* __restrict__ Wk, const float* __restrict__ bk,
    const float* __restrict__ Wv, const float* __restrict__ bv,
    float* __restrict__ qkv)
{
    __shared__ __align__(16) float As[32][132];  // [k][m], padded
    __shared__ __align__(16) float Bs[32][132];  // [k][n], padded

    const int jsel = blockIdx.y;
    const float* Wj   = (jsel == 0) ? Wq : (jsel == 1) ? Wk : Wv;
    const float* bias = (jsel == 0) ? bq : (jsel == 1) ? bk : bv;

    const int m0 = blockIdx.x * 128;
    const int t  = threadIdx.x;
    const int tx = t & 15;
    const int ty = t >> 4;

    float acc[8][8];
    #pragma unroll
    for (int i = 0; i < 8; ++i)
        #pragma unroll
        for (int j = 0; j < 8; ++j) acc[i][j] = 0.f;

    for (int k0 = 0; k0 < DIM_; k0 += 32) {
        #pragma unroll
        for (int p = 0; p < 4; ++p) {
            int slot = t + p * 256;
            int row  = slot >> 3;
            int c4   = slot & 7;
            float4 v = *(const float4*)&x[(size_t)(m0 + row) * DIM_ + k0 + c4 * 4];
            As[c4 * 4 + 0][row] = v.x;
            As[c4 * 4 + 1][row] = v.y;
            As[c4 * 4 + 2][row] = v.z;
            As[c4 * 4 + 3][row] = v.w;
        }
        #pragma unroll
        for (int p = 0; p < 4; ++p) {
            int slot = t + p * 256;
            int kr   = slot >> 5;
            int n4   = slot & 31;
            *(float4*)&Bs[kr][n4 * 4] =
                *(const float4*)&Wj[(size_t)(k0 + kr) * HD_ + n4 * 4];
        }
        __syncthreads();

        #pragma unroll 4
        for (int kk = 0; kk < 32; ++kk) {
            float a[8], b[8];
            *(float4*)&a[0] = *(const float4*)&As[kk][ty * 8];
            *(float4*)&a[4] = *(const float4*)&As[kk][ty * 8 + 4];
            *(float4*)&b[0] = *(const float4*)&Bs[kk][tx * 8];
            *(float4*)&b[4] = *(const float4*)&Bs[kk][tx * 8 + 4];
            #pragma unroll
            for (int i = 0; i < 8; ++i)
                #pragma unroll
                for (int j = 0; j < 8; ++j)
                    acc[i][j] = fmaf(a[i], b[j], acc[i][j]);
        }
        __syncthreads();
    }

    #pragma unroll
    for (int i = 0; i < 8; ++i) {
        int m = m0 + ty * 8 + i;
        int bb = m >> 11;
        int ss = m & 2047;
        size_t base = ((size_t)ss * B_ + bb) * 384 + jsel * 128 + tx * 8;
        #pragma unroll
        for (int j = 0; j < 8; ++j)
            qkv[base + j] = acc[i][j] + bias[tx * 8 + j];
    }
}

// ---------------------------------------------------------------------------
// Row-parallel sequential scan, pinned 4-deep register pipeline.
// One wave owns 8 rows of one batch (row = t>>3, 16-col chunk = t&7).
// asm memory clobbers stop the compiler from sinking the prefetch loads
// (round-2 failure mode: VGPR=84 proved the pipeline was de-scheduled).
// Addressing: one pointer per pipeline slot, bumped +4 steps after use;
// all intra-slot offsets are compile-time immediates.
// ---------------------------------------------------------------------------
__global__ __launch_bounds__(64) void scan_kernel(
    const float* __restrict__ qkv,   // [S][B][384]
    const float* __restrict__ state, // [B][128][128]
    const float* __restrict__ lrp,
    float* __restrict__ ys,          // [S][B][128]
    float* __restrict__ Wf)          // [B][128][128]
{
    const int b    = blockIdx.x & 7;    // batch -> XCD b (L2 locality)
    const int g    = blockIdx.x >> 3;   // row group 0..15
    const int t    = threadIdx.x;
    const int row  = t >> 3;            // 0..7
    const int ch   = t & 7;             // col chunk (16 cols)
    const int grow = g * 8 + row;       // global row 0..127
    const float lr = lrp[0];

    float w[16];
    {
        const float* wsrc = state + ((size_t)b * HD_ + grow) * HD_ + ch * 16;
        #pragma unroll
        for (int p = 0; p < 4; ++p)
            *(float4*)&w[p * 4] = *(const float4*)&wsrc[p * 4];
    }

    float Q[4][16], K[4][16], V[4];

    const int voff = 256 + grow - ch * 16;            // const per thread
    const float* p0 = qkv + (size_t)b * 384 + ch * 16;
    const float* p1 = p0 + 3072;
    const float* p2 = p0 + 2 * 3072;
    const float* p3 = p0 + 3 * 3072;
    float* py = ys + (size_t)b * HD_ + grow;          // +1024 floats/step

#define LOADSLOT(buf, ptr) do {                                            \
        _Pragma("unroll")                                                  \
        for (int pp_ = 0; pp_ < 4; ++pp_) {                                \
            *(float4*)&Q[buf][pp_ * 4] = *(const float4*)&(ptr)[pp_ * 4];        \
            *(float4*)&K[buf][pp_ * 4] = *(const float4*)&(ptr)[128 + pp_ * 4];  \
        }                                                                  \
        V[buf] = (ptr)[voff];                                              \
        (ptr) += 4 * 3072;                                                 \
        asm volatile("" ::: "memory");                                     \
    } while (0)

#define STEP(buf) do {                                                    \
        float e0 = 0.f, e1 = 0.f, e2 = 0.f, e3 = 0.f;                     \
        float y0 = 0.f, y1 = 0.f, y2 = 0.f, y3 = 0.f;                     \
        _Pragma("unroll")                                                 \
        for (int p = 0; p < 16; p += 4) {                                 \
            e0 = fmaf(w[p + 0], K[buf][p + 0], e0);                       \
            e1 = fmaf(w[p + 1], K[buf][p + 1], e1);                       \
            e2 = fmaf(w[p + 2], K[buf][p + 2], e2);                       \
            e3 = fmaf(w[p + 3], K[buf][p + 3], e3);                       \
            y0 = fmaf(w[p + 0], Q[buf][p + 0], y0);                       \
            y1 = fmaf(w[p + 1], Q[buf][p + 1], y1);                       \
            y2 = fmaf(w[p + 2], Q[buf][p + 2], y2);                       \
            y3 = fmaf(w[p + 3], Q[buf][p + 3], y3);                       \
        }                                                                 \
        float ep = (e0 + e1) + (e2 + e3);                                 \
        float yp = (y0 + y1) + (y2 + y3);                                 \
        ep += __shfl_xor(ep, 1);                                          \
        yp += __shfl_xor(yp, 1);                                          \
        ep += __shfl_xor(ep, 2);                                          \
        yp += __shfl_xor(yp, 2);                                          \
        ep += __shfl_xor(ep, 4);                                          \
        yp += __shfl_xor(yp, 4);                                          \
        float c = -lr * (ep - V[buf]);                                    \
        _Pragma("unroll")                                                 \
        for (int j = 0; j < 16; ++j)                                      \
            w[j] = fmaf(c, K[buf][j], w[j]);                              \
        if (ch == 0)                                                      \
            *py = yp;                                                     \
        py += B_ * HD_;                                                   \
    } while (0)

    // preload steps 0..3 (pointers advance to 4..7)
    LOADSLOT(0, p0);
    LOADSLOT(1, p1);
    LOADSLOT(2, p2);
    LOADSLOT(3, p3);

    // main loop: last iteration s = S_-8 prefetches s+7 = S_-1 (no clamp needed)
    #pragma unroll 1
    for (int s = 0; s < S_ - 4; s += 4) {
        STEP(0); LOADSLOT(0, p0);
        STEP(1); LOADSLOT(1, p1);
        STEP(2); LOADSLOT(2, p2);
        STEP(3); LOADSLOT(3, p3);
    }
    // tail: steps S_-4 .. S_-1, no prefetch
    STEP(0);
    STEP(1);
    STEP(2);
    STEP(3);

#undef LOADSLOT
#undef STEP

    {
        float* wd = Wf + ((size_t)b * HD_ + grow) * HD_ + ch * 16;
        #pragma unroll
        for (int p = 0; p < 4; ++p)
            *(float4*)&wd[p * 4] = *(const float4*)&w[p * 4];
    }
}

// ---------------------------------------------------------------------------
// Output projection: out[(b,s), n] = ys[s][b][:] @ Wo + bo
// ---------------------------------------------------------------------------
__global__ __launch_bounds__(256) void outproj_kernel(
    const float* __restrict__ ys,   // [S][B][128]
    const float* __restrict__ Wo,   // [128][2048]
    const float* __restrict__ bo,   // [2048]
    float* __restrict__ out)        // [B*S][2048]
{
    __shared__ __align__(16) float As[64][132];  // [k][m]
    __shared__ __align__(16) float Bs[64][132];  // [k][n]

    const int m0 = blockIdx.x * 128;
    const int n0 = blockIdx.y * 128;
    const int bb = m0 >> 11;
    const int s0 = m0 & 2047;
    const int t  = threadIdx.x;
    const int tx = t & 15;
    const int ty = t >> 4;

    float acc[8][8];
    #pragma unroll
    for (int i = 0; i < 8; ++i)
        #pragma unroll
        for (int j = 0; j < 8; ++j) acc[i][j] = 0.f;

    for (int k0 = 0; k0 < HD_; k0 += 64) {
        #pragma unroll
        for (int p = 0; p < 8; ++p) {
            int slot = t + p * 256;
            int row  = slot >> 4;
            int c4   = slot & 15;
            float4 v = *(const float4*)&ys[((size_t)(s0 + row) * B_ + bb) * HD_ + k0 + c4 * 4];
            As[c4 * 4 + 0][row] = v.x;
            As[c4 * 4 + 1][row] = v.y;
            As[c4 * 4 + 2][row] = v.z;
            As[c4 * 4 + 3][row] = v.w;
        }
        #pragma unroll
        for (int p = 0; p < 8; ++p) {
            int slot = t + p * 256;
            int kr   = slot >> 5;
            int n4   = slot & 31;
            *(float4*)&Bs[kr][n4 * 4] =
                *(const float4*)&Wo[(size_t)(k0 + kr) * DIM_ + n0 + n4 * 4];
        }
        __syncthreads();

        #pragma unroll 4
        for (int kk = 0; kk < 64; ++kk) {
            float a[8], bfr[8];
            *(float4*)&a[0]   = *(const float4*)&As[kk][ty * 8];
            *(float4*)&a[4]   = *(const float4*)&As[kk][ty * 8 + 4];
            *(float4*)&bfr[0] = *(const float4*)&Bs[kk][tx * 8];
            *(float4*)&bfr[4] = *(const float4*)&Bs[kk][tx * 8 + 4];
            #pragma unroll
            for (int i = 0; i < 8; ++i)
                #pragma unroll
                for (int j = 0; j < 8; ++j)
                    acc[i][j] = fmaf(a[i], bfr[j], acc[i][j]);
        }
        __syncthreads();
    }

    #pragma unroll
    for (int i = 0; i < 8; ++i) {
        size_t m = m0 + ty * 8 + i;
        #pragma unroll
        for (int j = 0; j < 8; ++j)
            out[m * DIM_ + n0 + tx * 8 + j] = acc[i][j] + bo[n0 + tx * 8 + j];
    }
}

// ---------------------------------------------------------------------------
extern "C" void kernel_launch(void* const* d_in, const int* in_sizes, int n_in,
                              void* d_out, int out_size, void* d_ws, size_t ws_size,
                              hipStream_t stream)
{
    const float* x  = (const float*)d_in[0];
    const float* st = (const float*)d_in[1];
    const float* Wq = (const float*)d_in[2];
    const float* bq = (const float*)d_in[3];
    const float* Wk = (const float*)d_in[4];
    const float* bk = (const float*)d_in[5];
    const float* Wv = (const float*)d_in[6];
    const float* bv = (const float*)d_in[7];
    const float* Wo = (const float*)d_in[8];
    const float* bo = (const float*)d_in[9];
    const float* lr = (const float*)d_in[10];

    float* out = (float*)d_out;
    float* Wf  = out + (size_t)B_ * S_ * DIM_;   // final state, after out

    float* qkv = (float*)d_ws;                   // [S][B][384]
    float* ys  = qkv + (size_t)S_ * B_ * 384;    // [S][B][128]

    dim3 gp(128, 3);
    proj_kernel<<<gp, 256, 0, stream>>>(x, Wq, bq, Wk, bk, Wv, bv, qkv);

    scan_kernel<<<128, 64, 0, stream>>>(qkv, st, lr, ys, Wf);

    dim3 go(128, 16);
    outproj_kernel<<<go, 256, 0, stream>>>(ys, Wo, bo, out);
}